// Round 1
// baseline (194.251 us; speedup 1.0000x reference)
//
#include <hip/hip_runtime.h>
#include <hip/hip_bf16.h>
#include <stdint.h>
#include <stddef.h>

// MMD loss via single signed 2N x 2N RBF gram, lower-triangle blocks only.
// Z = [X; Y] (bf16), sign(i) = +1 for i<N, -1 otherwise.
// result = (1/N^2) * sum_{i,j} s_i s_j exp(-(|zi|^2+|zj|^2-2 zi.zj)/sigma)

#define N_PTS   8192
#define DIM     256
#define TWO_N   16384
#define BM      128
#define BK      64
#define NBLK    128           // TWO_N / BM
#define NBLK_H  64            // boundary block-row between X and Y
#define TRI_BLOCKS (NBLK * (NBLK + 1) / 2)   // 8256

#define AS1 __attribute__((address_space(1)))
#define AS3 __attribute__((address_space(3)))

typedef __attribute__((ext_vector_type(8))) short short8;   // 8 x bf16 (4 VGPRs)
typedef __attribute__((ext_vector_type(4))) float f32x4;

// ---------------------------------------------------------------------------
// Prep: fp32 -> bf16 convert (row-major) + fp32 row norms. 1 wave per row.
// ---------------------------------------------------------------------------
__global__ __launch_bounds__(256) void mmd_prep(const float* __restrict__ X,
                                                const float* __restrict__ Y,
                                                __hip_bfloat16* __restrict__ Z,
                                                float* __restrict__ n2) {
    const int wave = threadIdx.x >> 6;
    const int lane = threadIdx.x & 63;
    const int row  = blockIdx.x * 4 + wave;          // 0 .. TWO_N-1

    const float* src = (row < N_PTS) ? (X + (size_t)row * DIM)
                                     : (Y + (size_t)(row - N_PTS) * DIM);
    float4 v = ((const float4*)src)[lane];           // 64 lanes x 4 = 256 elems

    float s = v.x * v.x + v.y * v.y + v.z * v.z + v.w * v.w;
#pragma unroll
    for (int off = 32; off; off >>= 1) s += __shfl_down(s, off, 64);
    if (lane == 0) n2[row] = s;

    union { unsigned short u[4]; uint2 q; } pk;
    __hip_bfloat16 h;
    h = __float2bfloat16(v.x); pk.u[0] = *(unsigned short*)&h;
    h = __float2bfloat16(v.y); pk.u[1] = *(unsigned short*)&h;
    h = __float2bfloat16(v.z); pk.u[2] = *(unsigned short*)&h;
    h = __float2bfloat16(v.w); pk.u[3] = *(unsigned short*)&h;
    *(uint2*)((char*)Z + (size_t)row * DIM * 2 + (size_t)lane * 8) = pk.q;
}

// ---------------------------------------------------------------------------
// Main: one 128x128 tile of the signed gram per block (lower triangle only).
// 256 threads = 4 waves; wave (wm,wn) owns a 64x64 subtile = 4x4 MFMA tiles.
// LDS tiles staged via global_load_lds width=16 with XOR chunk swizzle applied
// on the GLOBAL source index (keeps the wave-uniform LDS base contiguous).
// ---------------------------------------------------------------------------
__global__ __launch_bounds__(256) void mmd_main(const __hip_bfloat16* __restrict__ Z,
                                                const float* __restrict__ n2,
                                                const int* __restrict__ sigmap,
                                                float* __restrict__ out) {
    // A tile: chunks [0,1024)   (128 rows x 8 chunks of 16B)  = 16 KB
    // B tile: chunks [1024,2048)                              = 16 KB
    __shared__ short8 smem[2048];
    __shared__ float n2r[BM];
    __shared__ float n2c[BM];
    __shared__ float wsum[4];

    const int t    = threadIdx.x;
    const int wave = t >> 6;
    const int lane = t & 63;

    // decode lower-triangle block index: br >= bc
    int idx = (int)blockIdx.x;
    int r = (int)(sqrtf(2.0f * (float)idx + 0.25f) - 0.5f);
    while ((r + 1) * (r + 2) / 2 <= idx) ++r;
    while (r * (r + 1) / 2 > idx) --r;
    const int br = r;
    const int bc = idx - r * (r + 1) / 2;

    const int rowBase = br * BM;
    const int colBase = bc * BM;

    if (t < BM)           n2r[t]      = n2[rowBase + t];
    else if (t < 2 * BM)  n2c[t - BM] = n2[colBase + (t - BM)];

    f32x4 acc[4][4] = {};

    const int wm = wave >> 1;        // 0..1  (row half of 128)
    const int wn = wave & 1;         // 0..1  (col half)
    const int g  = lane >> 4;        // k-quad 0..3
    const int ml = lane & 15;        // m/n within 16

    char* smem_b = (char*)smem;

    for (int kt = 0; kt < 4; ++kt) {
        __syncthreads();             // previous iter's reads done before overwrite
        const int k0 = kt * BK;
#pragma unroll
        for (int p = 0; p < 4; ++p) {
            const int c   = p * 256 + wave * 64 + lane;   // linear 16B chunk 0..1023
            const int row = c >> 3;
            const int cs  = c & 7;
            const int gc  = cs ^ (row & 7);               // XOR swizzle on source
            const __hip_bfloat16* gA = Z + (size_t)(rowBase + row) * DIM + k0 + gc * 8;
            const __hip_bfloat16* gB = Z + (size_t)(colBase + row) * DIM + k0 + gc * 8;
            char* lA = smem_b + (size_t)(p * 256 + wave * 64) * 16;
            char* lB = lA + 16384;
            __builtin_amdgcn_global_load_lds((const AS1 void*)gA, (AS3 void*)lA, 16, 0, 0);
            __builtin_amdgcn_global_load_lds((const AS1 void*)gB, (AS3 void*)lB, 16, 0, 0);
        }
        __syncthreads();             // drain vmcnt, staging visible

#pragma unroll
        for (int ki = 0; ki < 2; ++ki) {
            short8 af[4], bf[4];
            const int j = ki * 4 + g;                     // k-chunk within BK
#pragma unroll
            for (int mt = 0; mt < 4; ++mt) {
                const int arow = wm * 64 + mt * 16 + ml;
                af[mt] = *(const short8*)(smem_b + (size_t)(arow * 8 + (j ^ (arow & 7))) * 16);
                const int bcol = wn * 64 + mt * 16 + ml;
                bf[mt] = *(const short8*)(smem_b + 16384 + (size_t)(bcol * 8 + (j ^ (bcol & 7))) * 16);
            }
#pragma unroll
            for (int mt = 0; mt < 4; ++mt)
#pragma unroll
                for (int nt = 0; nt < 4; ++nt)
                    acc[mt][nt] = __builtin_amdgcn_mfma_f32_16x16x32_bf16(
                        af[mt], bf[nt], acc[mt][nt], 0, 0, 0);
        }
    }

    // epilogue: w = exp2(-log2e/sigma * sq), signed+symmetry-weighted sum
    const float inv_sigma = 1.0f / (float)(*sigmap);
    const float c2 = -1.4426950408889634f * inv_sigma;

    float sum = 0.0f;
#pragma unroll
    for (int mt = 0; mt < 4; ++mt) {
#pragma unroll
        for (int nt = 0; nt < 4; ++nt) {
#pragma unroll
            for (int rr = 0; rr < 4; ++rr) {
                const int il = wm * 64 + mt * 16 + g * 4 + rr;  // C/D: row=(lane>>4)*4+reg
                const int jl = wn * 64 + nt * 16 + ml;          // C/D: col=lane&15
                const float d  = acc[mt][nt][rr];
                float sq = n2r[il] + n2c[jl] - 2.0f * d;
                sq = fmaxf(sq, 0.0f);                           // true sq >= 0
                sum += __builtin_amdgcn_exp2f(sq * c2);
            }
        }
    }

#pragma unroll
    for (int off = 32; off; off >>= 1) sum += __shfl_down(sum, off, 64);
    if (lane == 0) wsum[wave] = sum;
    __syncthreads();
    if (t == 0) {
        const float sign = ((br < NBLK_H) == (bc < NBLK_H)) ? 1.0f : -1.0f;
        const float mult = (br == bc) ? 1.0f : 2.0f;            // symmetry: count (j,i) too
        const float factor = sign * mult * (1.0f / 67108864.0f); // 1/N^2
        atomicAdd(out, (wsum[0] + wsum[1] + wsum[2] + wsum[3]) * factor);
    }
}

// ---------------------------------------------------------------------------
extern "C" void kernel_launch(void* const* d_in, const int* in_sizes, int n_in,
                              void* d_out, int out_size, void* d_ws, size_t ws_size,
                              hipStream_t stream) {
    const float* X      = (const float*)d_in[0];
    const float* Y      = (const float*)d_in[1];
    const int*   sigmap = (const int*)d_in[2];
    float*       out    = (float*)d_out;

    __hip_bfloat16* Z  = (__hip_bfloat16*)d_ws;                       // 8 MB
    float*          n2 = (float*)((char*)d_ws + (size_t)TWO_N * DIM * 2);

    hipMemsetAsync(d_out, 0, sizeof(float), stream);   // capture-safe memset node
    mmd_prep<<<TWO_N / 4, 256, 0, stream>>>(X, Y, Z, n2);
    mmd_main<<<TRI_BLOCKS, 256, 0, stream>>>(Z, n2, sigmap, out);
}

// Round 2
// 176.686 us; speedup vs baseline: 1.0994x; 1.0994x over previous
//
#include <hip/hip_runtime.h>
#include <hip/hip_bf16.h>
#include <stdint.h>
#include <stddef.h>

// MMD via single signed 2N x 2N RBF gram, lower triangle only.
// Round 2: A-stationary blocks. Block (br,c) owns 128-row strip br and
// column tiles bc = c, c+16, ... <= br. A fragments (full K=256) live in
// registers; B tiles stream through 64 KB LDS in two software-pipelined
// 32 KB halves. 2 barriers per tile (was 8), epilogue slimmed.

#define N_PTS   8192
#define DIM     256
#define TWO_N   16384
#define CSTRIDE 16

#define AS1 __attribute__((address_space(1)))
#define AS3 __attribute__((address_space(3)))

typedef __attribute__((ext_vector_type(8))) short short8;   // 8 x bf16
typedef __attribute__((ext_vector_type(4))) float f32x4;

// ---------------------------------------------------------------------------
// Prep: fp32 -> bf16 (row-major) + fp32 row norms + zero the output scalar.
// ---------------------------------------------------------------------------
__global__ __launch_bounds__(256) void mmd_prep(const float* __restrict__ X,
                                                const float* __restrict__ Y,
                                                __hip_bfloat16* __restrict__ Z,
                                                float* __restrict__ n2,
                                                float* __restrict__ out) {
    if (blockIdx.x == 0 && threadIdx.x == 0) out[0] = 0.0f;

    const int wave = threadIdx.x >> 6;
    const int lane = threadIdx.x & 63;
    const int row  = blockIdx.x * 4 + wave;          // 0 .. TWO_N-1

    const float* src = (row < N_PTS) ? (X + (size_t)row * DIM)
                                     : (Y + (size_t)(row - N_PTS) * DIM);
    float4 v = ((const float4*)src)[lane];           // 64 lanes x 4 = 256

    float s = v.x * v.x + v.y * v.y + v.z * v.z + v.w * v.w;
#pragma unroll
    for (int off = 32; off; off >>= 1) s += __shfl_down(s, off, 64);
    if (lane == 0) n2[row] = s;

    union { unsigned short u[4]; uint2 q; } pk;
    __hip_bfloat16 h;
    h = __float2bfloat16(v.x); pk.u[0] = *(unsigned short*)&h;
    h = __float2bfloat16(v.y); pk.u[1] = *(unsigned short*)&h;
    h = __float2bfloat16(v.z); pk.u[2] = *(unsigned short*)&h;
    h = __float2bfloat16(v.w); pk.u[3] = *(unsigned short*)&h;
    *(uint2*)((char*)Z + (size_t)row * DIM * 2 + (size_t)lane * 8) = pk.q;
}

// ---------------------------------------------------------------------------
// Main. grid = 128*16 blocks; br = 127 - (bid>>4) (heavy blocks first),
// c = bid & 15; empty blocks (c > br) exit.
// 4 waves, wave (wm,wn) owns 64x64 of the 128x128 tile via 4x4 MFMA 16x16x32.
// ---------------------------------------------------------------------------
__global__ __launch_bounds__(256, 2) void mmd_main(const __hip_bfloat16* __restrict__ Z,
                                                   const float* __restrict__ n2,
                                                   const int* __restrict__ sigmap,
                                                   float* __restrict__ out) {
    __shared__ short8 bsm[4096];    // [2 halves][128 rows][16 chunks] 16B, XOR swizzle
    __shared__ float wsum[4];

    const int bid = (int)blockIdx.x;
    const int br  = 127 - (bid >> 4);
    const int cc  = bid & 15;
    if (cc > br) return;

    const int t    = threadIdx.x;
    const int wave = t >> 6;
    const int lane = t & 63;
    const int wm   = wave >> 1;
    const int wn   = wave & 1;
    const int g    = lane >> 4;
    const int ml   = lane & 15;
    const int rowBase = br * 128;

    const float inv_sigma = 1.0f / (float)(*sigmap);
    const float c2 = -1.4426950408889634f * inv_sigma;   // -log2e/sigma
    const float m2 = -2.0f * c2;

    char* smem_b = (char*)bsm;

    // ---- stage B half 0 of the FIRST tile (overlaps A-frag loads below) ----
    {
        const int colBase0 = cc * 128;
#pragma unroll
        for (int i = 0; i < 8; ++i) {
            const int cidx = i * 256 + t;            // 0..2047
            const int row  = cidx >> 4;
            const int s    = cidx & 15;
            const int gc   = s ^ (row & 7);
            const __hip_bfloat16* gp = Z + (size_t)(colBase0 + row) * DIM + gc * 8;
            __builtin_amdgcn_global_load_lds((const AS1 void*)gp,
                                             (AS3 void*)(smem_b + (size_t)cidx * 16), 16, 0, 0);
        }
    }

    // ---- A fragments (full K) into registers, once per block ----
    short8 af[4][8];
#pragma unroll
    for (int mt = 0; mt < 4; ++mt) {
        const __hip_bfloat16* rp = Z + (size_t)(rowBase + wm * 64 + mt * 16 + ml) * DIM + g * 8;
#pragma unroll
        for (int kc = 0; kc < 8; ++kc)
            af[mt][kc] = *(const short8*)(rp + kc * 32);
    }
    // row-norm coefficients: a_i = c2 * |z_i|^2 for this lane's 16 C-rows
    float a_i[4][4];
#pragma unroll
    for (int mt = 0; mt < 4; ++mt)
#pragma unroll
        for (int rr = 0; rr < 4; ++rr)
            a_i[mt][rr] = c2 * n2[rowBase + wm * 64 + mt * 16 + g * 4 + rr];

    float block_acc = 0.0f;
    const int brX = (br < 64);

    for (int bc = cc; bc <= br; bc += CSTRIDE) {
        const int colBase = bc * 128;

        // column-norm coefficients for this tile (issue early)
        float b_j[4];
#pragma unroll
        for (int nt = 0; nt < 4; ++nt)
            b_j[nt] = c2 * n2[colBase + wn * 64 + nt * 16 + ml];

        f32x4 acc[4][4] = {};

        __syncthreads();                 // B half0 of this tile landed

        // ---- stage B half 1 (overlaps h0 compute) ----
#pragma unroll
        for (int i = 0; i < 8; ++i) {
            const int cidx = i * 256 + t;
            const int row  = cidx >> 4;
            const int s    = cidx & 15;
            const int gc   = s ^ (row & 7);
            const __hip_bfloat16* gp = Z + (size_t)(colBase + row) * DIM + 128 + gc * 8;
            __builtin_amdgcn_global_load_lds((const AS1 void*)gp,
                                             (AS3 void*)(smem_b + 32768 + (size_t)cidx * 16), 16, 0, 0);
        }

        // ---- compute on half 0 (k = 0..127) ----
#pragma unroll
        for (int kc2 = 0; kc2 < 4; ++kc2) {
            short8 bf[4];
#pragma unroll
            for (int nt = 0; nt < 4; ++nt) {
                const int rz = wn * 64 + nt * 16 + ml;
                bf[nt] = bsm[rz * 16 + ((kc2 * 4 + g) ^ (rz & 7))];
            }
#pragma unroll
            for (int mt = 0; mt < 4; ++mt)
#pragma unroll
                for (int nt = 0; nt < 4; ++nt)
                    acc[mt][nt] = __builtin_amdgcn_mfma_f32_16x16x32_bf16(
                        af[mt][kc2], bf[nt], acc[mt][nt], 0, 0, 0);
        }

        __syncthreads();                 // half1 landed; everyone done reading half0

        // ---- stage B half 0 of NEXT tile (overlaps h1 compute + epilogue) ----
        if (bc + CSTRIDE <= br) {
            const int colBaseN = colBase + CSTRIDE * 128;
#pragma unroll
            for (int i = 0; i < 8; ++i) {
                const int cidx = i * 256 + t;
                const int row  = cidx >> 4;
                const int s    = cidx & 15;
                const int gc   = s ^ (row & 7);
                const __hip_bfloat16* gp = Z + (size_t)(colBaseN + row) * DIM + gc * 8;
                __builtin_amdgcn_global_load_lds((const AS1 void*)gp,
                                                 (AS3 void*)(smem_b + (size_t)cidx * 16), 16, 0, 0);
            }
        }

        // ---- compute on half 1 (k = 128..255) ----
#pragma unroll
        for (int kc2 = 0; kc2 < 4; ++kc2) {
            short8 bf[4];
#pragma unroll
            for (int nt = 0; nt < 4; ++nt) {
                const int rz = wn * 64 + nt * 16 + ml;
                bf[nt] = bsm[2048 + rz * 16 + ((kc2 * 4 + g) ^ (rz & 7))];
            }
#pragma unroll
            for (int mt = 0; mt < 4; ++mt)
#pragma unroll
                for (int nt = 0; nt < 4; ++nt)
                    acc[mt][nt] = __builtin_amdgcn_mfma_f32_16x16x32_bf16(
                        af[mt][4 + kc2], bf[nt], acc[mt][nt], 0, 0, 0);
        }

        // ---- epilogue: sum exp2(c2*(n2i+n2j) + m2*dot), weighted ----
        float tsum = 0.0f;
#pragma unroll
        for (int mt = 0; mt < 4; ++mt)
#pragma unroll
            for (int nt = 0; nt < 4; ++nt) {
#pragma unroll
                for (int rr = 0; rr < 4; ++rr)
                    tsum += __builtin_amdgcn_exp2f(
                        fmaf(acc[mt][nt][rr], m2, a_i[mt][rr] + b_j[nt]));
            }
        const float sgn = ((bc < 64) == brX) ? 1.0f : -1.0f;
        const float w   = (bc == br) ? sgn : 2.0f * sgn;   // symmetry weight
        block_acc = fmaf(w, tsum, block_acc);
    }

    // ---- block reduction + single atomic ----
    float s = block_acc;
#pragma unroll
    for (int off = 32; off; off >>= 1) s += __shfl_down(s, off, 64);
    if (lane == 0) wsum[wave] = s;
    __syncthreads();
    if (t == 0)
        atomicAdd(out, (wsum[0] + wsum[1] + wsum[2] + wsum[3]) * (1.0f / 67108864.0f));
}

// ---------------------------------------------------------------------------
extern "C" void kernel_launch(void* const* d_in, const int* in_sizes, int n_in,
                              void* d_out, int out_size, void* d_ws, size_t ws_size,
                              hipStream_t stream) {
    const float* X      = (const float*)d_in[0];
    const float* Y      = (const float*)d_in[1];
    const int*   sigmap = (const int*)d_in[2];
    float*       out    = (float*)d_out;

    __hip_bfloat16* Z  = (__hip_bfloat16*)d_ws;                       // 8 MB
    float*          n2 = (float*)((char*)d_ws + (size_t)TWO_N * DIM * 2);

    mmd_prep<<<TWO_N / 4, 256, 0, stream>>>(X, Y, Z, n2, out);
    mmd_main<<<128 * CSTRIDE, 256, 0, stream>>>(Z, n2, sigmap, out);
}

// Round 3
// 146.222 us; speedup vs baseline: 1.3285x; 1.2083x over previous
//
#include <hip/hip_runtime.h>
#include <hip/hip_bf16.h>
#include <stdint.h>
#include <stddef.h>

// MMD via single signed 2N x 2N RBF gram, lower triangle only.
// Round 3: same A-stationary / B-through-LDS structure as round 2, but wave
// tiling changed 2x2(64x64) -> 4x1(32x128) so A fragments are 64 VGPRs
// (was 128): total register demand ~200 < 256 unified budget -> no spill
// (round 2 spilled ~62 MB of scratch stores, the measured bottleneck).

#define N_PTS   8192
#define DIM     256
#define TWO_N   16384
#define CSTRIDE 16

#define AS1 __attribute__((address_space(1)))
#define AS3 __attribute__((address_space(3)))

typedef __attribute__((ext_vector_type(8))) short short8;   // 8 x bf16
typedef __attribute__((ext_vector_type(4))) float f32x4;

// ---------------------------------------------------------------------------
// Prep: fp32 -> bf16 (row-major) + fp32 row norms + zero the output scalar.
// ---------------------------------------------------------------------------
__global__ __launch_bounds__(256) void mmd_prep(const float* __restrict__ X,
                                                const float* __restrict__ Y,
                                                __hip_bfloat16* __restrict__ Z,
                                                float* __restrict__ n2,
                                                float* __restrict__ out) {
    if (blockIdx.x == 0 && threadIdx.x == 0) out[0] = 0.0f;

    const int wave = threadIdx.x >> 6;
    const int lane = threadIdx.x & 63;
    const int row  = blockIdx.x * 4 + wave;          // 0 .. TWO_N-1

    const float* src = (row < N_PTS) ? (X + (size_t)row * DIM)
                                     : (Y + (size_t)(row - N_PTS) * DIM);
    float4 v = ((const float4*)src)[lane];           // 64 lanes x 4 = 256

    float s = v.x * v.x + v.y * v.y + v.z * v.z + v.w * v.w;
#pragma unroll
    for (int off = 32; off; off >>= 1) s += __shfl_down(s, off, 64);
    if (lane == 0) n2[row] = s;

    union { unsigned short u[4]; uint2 q; } pk;
    __hip_bfloat16 h;
    h = __float2bfloat16(v.x); pk.u[0] = *(unsigned short*)&h;
    h = __float2bfloat16(v.y); pk.u[1] = *(unsigned short*)&h;
    h = __float2bfloat16(v.z); pk.u[2] = *(unsigned short*)&h;
    h = __float2bfloat16(v.w); pk.u[3] = *(unsigned short*)&h;
    *(uint2*)((char*)Z + (size_t)row * DIM * 2 + (size_t)lane * 8) = pk.q;
}

// ---------------------------------------------------------------------------
// Main. grid = 128*16 blocks; br = 127 - (bid>>4) (heavy blocks first),
// cc = bid & 15; empty blocks (cc > br) exit.
// 4 waves; wave w owns rows [w*32, w*32+32) x all 128 cols:
// 2 (mt) x 8 (nt) MFMA tiles of 16x16x32.
// ---------------------------------------------------------------------------
__global__ __launch_bounds__(256, 2) void mmd_main(const __hip_bfloat16* __restrict__ Z,
                                                   const float* __restrict__ n2,
                                                   const int* __restrict__ sigmap,
                                                   float* __restrict__ out) {
    __shared__ short8 bsm[4096];    // [2 halves][128 cols][16 k-chunks], XOR swizzle
    __shared__ float wsum[4];

    const int bid = (int)blockIdx.x;
    const int br  = 127 - (bid >> 4);
    const int cc  = bid & 15;
    if (cc > br) return;

    const int t    = threadIdx.x;
    const int wave = t >> 6;
    const int lane = t & 63;
    const int g    = lane >> 4;      // k-quad / C-row group
    const int ml   = lane & 15;
    const int rowBase = br * 128;

    const float inv_sigma = 1.0f / (float)(*sigmap);
    const float c2 = -1.4426950408889634f * inv_sigma;   // -log2e/sigma
    const float m2 = -2.0f * c2;

    char* smem_b = (char*)bsm;

    // ---- stage B half 0 of the FIRST tile (overlaps A-frag loads below) ----
    {
        const int colBase0 = cc * 128;
#pragma unroll
        for (int i = 0; i < 8; ++i) {
            const int cidx = i * 256 + t;            // 0..2047
            const int row  = cidx >> 4;              // col index j
            const int s    = cidx & 15;              // LDS k-chunk slot
            const int gc   = s ^ (row & 7);          // XOR swizzle on source
            const __hip_bfloat16* gp = Z + (size_t)(colBase0 + row) * DIM + gc * 8;
            __builtin_amdgcn_global_load_lds((const AS1 void*)gp,
                                             (AS3 void*)(smem_b + (size_t)cidx * 16), 16, 0, 0);
        }
    }

    // ---- A fragments (full K, 32 rows) into registers, once per block ----
    short8 af[2][8];                 // 64 VGPRs
#pragma unroll
    for (int mt = 0; mt < 2; ++mt) {
        const __hip_bfloat16* rp =
            Z + (size_t)(rowBase + wave * 32 + mt * 16 + ml) * DIM + g * 8;
#pragma unroll
        for (int kc = 0; kc < 8; ++kc)
            af[mt][kc] = *(const short8*)(rp + kc * 32);
    }
    // row-norm coefficients: a_i = c2 * |z_i|^2 for this lane's C rows
    float a_i[2][4];
#pragma unroll
    for (int mt = 0; mt < 2; ++mt)
#pragma unroll
        for (int rr = 0; rr < 4; ++rr)
            a_i[mt][rr] = c2 * n2[rowBase + wave * 32 + mt * 16 + g * 4 + rr];

    float block_acc = 0.0f;
    const int brX = (br < 64);

    for (int bc = cc; bc <= br; bc += CSTRIDE) {
        const int colBase = bc * 128;

        // column-norm coefficients for this tile (issue early)
        float b_j[8];
#pragma unroll
        for (int nt = 0; nt < 8; ++nt)
            b_j[nt] = c2 * n2[colBase + nt * 16 + ml];

        f32x4 acc[2][8] = {};

        __syncthreads();                 // B half0 of this tile landed

        // ---- stage B half 1 (overlaps h0 compute) ----
#pragma unroll
        for (int i = 0; i < 8; ++i) {
            const int cidx = i * 256 + t;
            const int row  = cidx >> 4;
            const int s    = cidx & 15;
            const int gc   = s ^ (row & 7);
            const __hip_bfloat16* gp = Z + (size_t)(colBase + row) * DIM + 128 + gc * 8;
            __builtin_amdgcn_global_load_lds((const AS1 void*)gp,
                                             (AS3 void*)(smem_b + 32768 + (size_t)cidx * 16), 16, 0, 0);
        }

        // ---- compute on half 0 (k = 0..127) ----
#pragma unroll
        for (int kc2 = 0; kc2 < 4; ++kc2) {
            const int j = kc2 * 4 + g;
            short8 bf[8];
#pragma unroll
            for (int nt = 0; nt < 8; ++nt) {
                const int rz = nt * 16 + ml;
                bf[nt] = bsm[rz * 16 + (j ^ (rz & 7))];
            }
#pragma unroll
            for (int mt = 0; mt < 2; ++mt)
#pragma unroll
                for (int nt = 0; nt < 8; ++nt)
                    acc[mt][nt] = __builtin_amdgcn_mfma_f32_16x16x32_bf16(
                        af[mt][kc2], bf[nt], acc[mt][nt], 0, 0, 0);
        }

        __syncthreads();                 // half1 landed; all done reading half0

        // ---- stage B half 0 of NEXT tile (overlaps h1 compute + epilogue) ----
        if (bc + CSTRIDE <= br) {
            const int colBaseN = colBase + CSTRIDE * 128;
#pragma unroll
            for (int i = 0; i < 8; ++i) {
                const int cidx = i * 256 + t;
                const int row  = cidx >> 4;
                const int s    = cidx & 15;
                const int gc   = s ^ (row & 7);
                const __hip_bfloat16* gp = Z + (size_t)(colBaseN + row) * DIM + gc * 8;
                __builtin_amdgcn_global_load_lds((const AS1 void*)gp,
                                                 (AS3 void*)(smem_b + (size_t)cidx * 16), 16, 0, 0);
            }
        }

        // ---- compute on half 1 (k = 128..255) ----
#pragma unroll
        for (int kc2 = 0; kc2 < 4; ++kc2) {
            const int j = kc2 * 4 + g;
            short8 bf[8];
#pragma unroll
            for (int nt = 0; nt < 8; ++nt) {
                const int rz = nt * 16 + ml;
                bf[nt] = bsm[2048 + rz * 16 + (j ^ (rz & 7))];
            }
#pragma unroll
            for (int mt = 0; mt < 2; ++mt)
#pragma unroll
                for (int nt = 0; nt < 8; ++nt)
                    acc[mt][nt] = __builtin_amdgcn_mfma_f32_16x16x32_bf16(
                        af[mt][4 + kc2], bf[nt], acc[mt][nt], 0, 0, 0);
        }

        // ---- epilogue: sum exp2(c2*(n2i+n2j) + m2*dot), weighted ----
        float tsum = 0.0f;
#pragma unroll
        for (int mt = 0; mt < 2; ++mt)
#pragma unroll
            for (int nt = 0; nt < 8; ++nt)
#pragma unroll
                for (int rr = 0; rr < 4; ++rr)
                    tsum += __builtin_amdgcn_exp2f(
                        fmaf(acc[mt][nt][rr], m2, a_i[mt][rr] + b_j[nt]));

        const float sgn = ((bc < 64) == brX) ? 1.0f : -1.0f;
        const float w   = (bc == br) ? sgn : 2.0f * sgn;   // symmetry weight
        block_acc = fmaf(w, tsum, block_acc);
    }

    // ---- block reduction + single atomic ----
    float s = block_acc;
#pragma unroll
    for (int off = 32; off; off >>= 1) s += __shfl_down(s, off, 64);
    if (lane == 0) wsum[wave] = s;
    __syncthreads();
    if (t == 0)
        atomicAdd(out, (wsum[0] + wsum[1] + wsum[2] + wsum[3]) * (1.0f / 67108864.0f));
}

// ---------------------------------------------------------------------------
extern "C" void kernel_launch(void* const* d_in, const int* in_sizes, int n_in,
                              void* d_out, int out_size, void* d_ws, size_t ws_size,
                              hipStream_t stream) {
    const float* X      = (const float*)d_in[0];
    const float* Y      = (const float*)d_in[1];
    const int*   sigmap = (const int*)d_in[2];
    float*       out    = (float*)d_out;

    __hip_bfloat16* Z  = (__hip_bfloat16*)d_ws;                       // 8 MB
    float*          n2 = (float*)((char*)d_ws + (size_t)TWO_N * DIM * 2);

    mmd_prep<<<TWO_N / 4, 256, 0, stream>>>(X, Y, Z, n2, out);
    mmd_main<<<128 * CSTRIDE, 256, 0, stream>>>(Z, n2, sigmap, out);
}